// Round 3
// baseline (80.675 us; speedup 1.0000x reference)
//
#include <hip/hip_runtime.h>

// FeatureLayer: out[row] = concat( sum_k W_item[item_hist[row,k]],        (64)
//                                  mean_k W_cate[cate_hist[row,k]],       (64)
//                                  concat_k W_ctx[ctx_ids[row,k]],        (640)
//                                  price[row],                            (1)
//                                  dense_vec[row] )                       (128)
// padding_idx = 0: index 0 contributes zeros. Mean divides by L=50 incl. padding.

#define LH 50      // item/cate history length
#define LC 20      // ctx length
#define DI 64      // item emb dim
#define DC 64      // cate emb dim
#define DX 32      // ctx emb dim
#define DDENSE 128
#define OUT_D 897  // 64 + 64 + 640 + 1 + 128
#define NIT 13     // ceil(LH/4)

typedef float f32x4 __attribute__((ext_vector_type(4)));

__global__ __launch_bounds__(256) void featlayer_kernel(
    const int* __restrict__ item_hist,
    const int* __restrict__ cate_hist,
    const int* __restrict__ ctx_ids,
    const float* __restrict__ price,
    const float* __restrict__ dense_vec,
    const float* __restrict__ W_item,
    const float* __restrict__ W_cate,
    const float* __restrict__ W_ctx,
    float* __restrict__ out,
    int B)
{
    const int wave = threadIdx.x >> 6;
    const int lane = threadIdx.x & 63;
    const int row  = blockIdx.x * 4 + wave;
    if (row >= B) return;

    const int sub = lane >> 4;   // 0..3 : which index within a group of 4
    const int l16 = lane & 15;   // 0..15: which float4 of the 64-wide emb row

    float* __restrict__ orow = out + (size_t)row * OUT_D;

    // ---------------- item (sum) + cate (mean) fused: max MLP ----------------
    {
        const int* __restrict__ ih = item_hist + row * LH;
        const int* __restrict__ ch = cate_hist + row * LH;

        // Preload all indices this sub-group needs (tail -> 0 == padding row,
        // contributes zero via the predicate below).
        int idxI[NIT], idxC[NIT];
        #pragma unroll
        for (int k = 0; k < NIT; ++k) {
            const int ki = sub + 4 * k;
            idxI[k] = (ki < LH) ? __builtin_nontemporal_load(ih + ki) : 0;
            idxC[k] = (ki < LH) ? __builtin_nontemporal_load(ch + ki) : 0;
        }

        f32x4 iacc = {0.f, 0.f, 0.f, 0.f};
        f32x4 cacc = {0.f, 0.f, 0.f, 0.f};
        #pragma unroll
        for (int k = 0; k < NIT; ++k) {
            const f32x4 vi = *reinterpret_cast<const f32x4*>(
                W_item + ((size_t)idxI[k] * DI + l16 * 4));
            const f32x4 vc = *reinterpret_cast<const f32x4*>(
                W_cate + ((size_t)idxC[k] * DC + l16 * 4));
            const float si = (idxI[k] != 0) ? 1.0f : 0.0f;  // padding_idx
            const float sc = (idxC[k] != 0) ? 1.0f : 0.0f;
            iacc += vi * si;
            cacc += vc * sc;
        }

        // combine 4 sub-group partials (lanes l, l+16, l+32, l+48)
        #pragma unroll
        for (int e = 0; e < 4; ++e) {
            float a = iacc[e];
            a += __shfl_xor(a, 16, 64);
            a += __shfl_xor(a, 32, 64);
            iacc[e] = a;
            float c = cacc[e];
            c += __shfl_xor(c, 16, 64);
            c += __shfl_xor(c, 32, 64);
            cacc[e] = c;
        }

        if (sub == 0) {
            __builtin_nontemporal_store(iacc,
                reinterpret_cast<f32x4*>(orow + l16 * 4));
            const float inv = 1.0f / (float)LH;  // mean divides by L incl. padding
            cacc *= inv;
            __builtin_nontemporal_store(cacc,
                reinterpret_cast<f32x4*>(orow + DI + l16 * 4));
        }
    }

    // ---------------- ctx: concat merger (640 floats) ----------------
    {
        const int* __restrict__ cids = ctx_ids + row * LC;
        #pragma unroll
        for (int j = lane; j < LC * DX; j += 64) {
            const int idx = cids[j >> 5];           // which of the 20 ids (broadcast)
            const int d   = j & 31;                 // dim within 32
            const float v = (idx != 0) ? W_ctx[idx * DX + d] : 0.0f;
            __builtin_nontemporal_store(v, orow + DI + DC + j);
        }
    }

    // ---------------- price (1) + dense (128) ----------------
    if (lane == 0)
        __builtin_nontemporal_store(price[row], orow + DI + DC + LC * DX);
    {
        const float* __restrict__ dv = dense_vec + (size_t)row * DDENSE;
        const float d0 = __builtin_nontemporal_load(dv + lane);
        const float d1 = __builtin_nontemporal_load(dv + 64 + lane);
        __builtin_nontemporal_store(d0, orow + DI + DC + LC * DX + 1 + lane);
        __builtin_nontemporal_store(d1, orow + DI + DC + LC * DX + 1 + 64 + lane);
    }
}

extern "C" void kernel_launch(void* const* d_in, const int* in_sizes, int n_in,
                              void* d_out, int out_size, void* d_ws, size_t ws_size,
                              hipStream_t stream) {
    const int*   item_hist = (const int*)  d_in[0];
    const int*   cate_hist = (const int*)  d_in[1];
    const int*   ctx_ids   = (const int*)  d_in[2];
    const float* price     = (const float*)d_in[3];
    const float* dense_vec = (const float*)d_in[4];
    const float* W_item    = (const float*)d_in[5];
    const float* W_cate    = (const float*)d_in[6];
    const float* W_ctx     = (const float*)d_in[7];
    float* out = (float*)d_out;

    const int B = in_sizes[0] / LH;         // 16384
    const int grid = (B + 3) / 4;           // 4 rows per 256-thread block
    featlayer_kernel<<<grid, 256, 0, stream>>>(
        item_hist, cate_hist, ctx_ids, price, dense_vec,
        W_item, W_cate, W_ctx, out, B);
}

// Round 4
// 76.213 us; speedup vs baseline: 1.0586x; 1.0586x over previous
//
#include <hip/hip_runtime.h>

// FeatureLayer: out[row] = concat( sum_k W_item[item_hist[row,k]],        (64)
//                                  mean_k W_cate[cate_hist[row,k]],       (64)
//                                  concat_k W_ctx[ctx_ids[row,k]],        (640)
//                                  price[row],                            (1)
//                                  dense_vec[row] )                       (128)
// padding_idx = 0: index 0 contributes zeros. Mean divides by L=50 incl. padding.

#define LH 50      // item/cate history length
#define LC 20      // ctx length
#define DI 64      // item emb dim
#define DC 64      // cate emb dim
#define DX 32      // ctx emb dim
#define DDENSE 128
#define OUT_D 897  // 64 + 64 + 640 + 1 + 128
#define NIT 13     // ceil(LH/4)

typedef float f32x4 __attribute__((ext_vector_type(4)));

__global__ __launch_bounds__(256) void featlayer_kernel(
    const int* __restrict__ item_hist,
    const int* __restrict__ cate_hist,
    const int* __restrict__ ctx_ids,
    const float* __restrict__ price,
    const float* __restrict__ dense_vec,
    const float* __restrict__ W_item,
    const float* __restrict__ W_cate,
    const float* __restrict__ W_ctx,
    float* __restrict__ out,
    int B)
{
    const int wave = threadIdx.x >> 6;
    const int lane = threadIdx.x & 63;
    const int row  = blockIdx.x * 4 + wave;
    if (row >= B) return;

    const int sub = lane >> 4;   // 0..3 : which index within a group of 4
    const int l16 = lane & 15;   // 0..15: which float4 of the 64-wide emb row

    float* __restrict__ orow = out + (size_t)row * OUT_D;

    // ---- load all indices first (2 cache lines per table per row) ----
    const int* __restrict__ ih = item_hist + row * LH;
    const int* __restrict__ ch = cate_hist + row * LH;
    int idxI[NIT], idxC[NIT];
    #pragma unroll
    for (int k = 0; k < NIT; ++k) {
        const int ki = sub + 4 * k;
        idxI[k] = (ki < LH) ? ih[ki] : 0;   // tail -> padding row 0
        idxC[k] = (ki < LH) ? ch[ki] : 0;
    }

    // ---- streaming loads issued early so they overlap gather latency ----
    const float* __restrict__ dv = dense_vec + (size_t)row * DDENSE;
    const float d0 = dv[lane];
    const float d1 = dv[64 + lane];
    const float pr = price[row];           // wave-uniform-ish, cheap
    const int* __restrict__ cids = ctx_ids + row * LC;

    // ---- stage ALL 26 gathers into registers: max misses in flight ----
    f32x4 vi[NIT], vc[NIT];
    #pragma unroll
    for (int k = 0; k < NIT; ++k) {
        vi[k] = *reinterpret_cast<const f32x4*>(
            W_item + ((size_t)idxI[k] * DI + l16 * 4));
        vc[k] = *reinterpret_cast<const f32x4*>(
            W_cate + ((size_t)idxC[k] * DC + l16 * 4));
    }

    f32x4 iacc = {0.f, 0.f, 0.f, 0.f};
    f32x4 cacc = {0.f, 0.f, 0.f, 0.f};
    #pragma unroll
    for (int k = 0; k < NIT; ++k) {
        const float si = (idxI[k] != 0) ? 1.0f : 0.0f;  // padding_idx
        const float sc = (idxC[k] != 0) ? 1.0f : 0.0f;
        iacc += vi[k] * si;
        cacc += vc[k] * sc;
    }

    // combine 4 sub-group partials (lanes l, l+16, l+32, l+48)
    #pragma unroll
    for (int e = 0; e < 4; ++e) {
        float a = iacc[e];
        a += __shfl_xor(a, 16, 64);
        a += __shfl_xor(a, 32, 64);
        iacc[e] = a;
        float c = cacc[e];
        c += __shfl_xor(c, 16, 64);
        c += __shfl_xor(c, 32, 64);
        cacc[e] = c;
    }

    if (sub == 0) {
        *reinterpret_cast<f32x4*>(orow + l16 * 4) = iacc;
        const float inv = 1.0f / (float)LH;  // mean divides by L incl. padding
        cacc *= inv;
        *reinterpret_cast<f32x4*>(orow + DI + l16 * 4) = cacc;
    }

    // ---------------- ctx: concat merger (640 floats) ----------------
    #pragma unroll
    for (int j = lane; j < LC * DX; j += 64) {
        const int idx = cids[j >> 5];           // which of the 20 ids (broadcast)
        const int d   = j & 31;                 // dim within 32
        orow[DI + DC + j] = (idx != 0) ? W_ctx[idx * DX + d] : 0.0f;
    }

    // ---------------- price (1) + dense (128) ----------------
    if (lane == 0) orow[DI + DC + LC * DX] = pr;
    orow[DI + DC + LC * DX + 1 + lane]      = d0;
    orow[DI + DC + LC * DX + 1 + 64 + lane] = d1;
}

extern "C" void kernel_launch(void* const* d_in, const int* in_sizes, int n_in,
                              void* d_out, int out_size, void* d_ws, size_t ws_size,
                              hipStream_t stream) {
    const int*   item_hist = (const int*)  d_in[0];
    const int*   cate_hist = (const int*)  d_in[1];
    const int*   ctx_ids   = (const int*)  d_in[2];
    const float* price     = (const float*)d_in[3];
    const float* dense_vec = (const float*)d_in[4];
    const float* W_item    = (const float*)d_in[5];
    const float* W_cate    = (const float*)d_in[6];
    const float* W_ctx     = (const float*)d_in[7];
    float* out = (float*)d_out;

    const int B = in_sizes[0] / LH;         // 16384
    const int grid = (B + 3) / 4;           // 4 rows per 256-thread block
    featlayer_kernel<<<grid, 256, 0, stream>>>(
        item_hist, cate_hist, ctx_ids, price, dense_vec,
        W_item, W_cate, W_ctx, out, B);
}